// Round 15
// baseline (124.627 us; speedup 1.0000x reference)
//
#include <hip/hip_runtime.h>

typedef unsigned short u16;
typedef __attribute__((ext_vector_type(8))) short short8;
typedef __attribute__((ext_vector_type(4))) float f32x4;

#define DIM    256
#define NE     8192
#define NROWS  8192
#define DECAY  0.1f
#define EPS_F  1e-5f
#define CRANGES 16      // column ranges of 512
#define CTILES  32      // 16-col tiles per range
#define MQ      384u    // refine margin: 1.5 distance units (q step = 1/256)

// output offsets (floats): quantize_st, embed_ind, loss, embed_normalized, cluster_size_new, embed_avg_new
#define OUT_Q    0
#define OUT_IND  2097152
#define OUT_LOSS 2105344
#define OUT_NORM 2105345
#define OUT_CSN  4202497
#define OUT_AVG  4210689

// ws offsets (bytes)
#define WS_CAND  65536      // u32[8192*32] top-2 per (row, range)
#define WS_ENORM 1114112    // f32[8192]
#define WS_BASEQ 1146880    // f32[8192]  (enorm + 512) * 256
#define WS_SUM   1179648    // f32[8192*256] transposed segment sums
#define WS_BINS  9568256    // f32[8192]
#define WS_LOSS  9601024    // f64
#define WS_SCS   9601032    // f64  sum(cluster_size)
#define WS_XB    9601040    // bf16[8192*256]
#define WS_ETB   13795344   // bf16[8192*256] E^T (k-contiguous)
#define WS_ET32  17989648   // f32[8192*256]  E^T
#define ZERO_F4  ((WS_LOSS - WS_SUM) / 16)  // prep zero-blocks: ws_sum + bins ONLY

__device__ __forceinline__ unsigned f32_ord(float f)
{
    unsigned u = __float_as_uint(f);
    return (u & 0x80000000u) ? ~u : (u | 0x80000000u);
}
__device__ __forceinline__ u16 bf16rne(float f)
{
    unsigned u = __float_as_uint(f);
    return (u16)((u + 0x7fffu + ((u >> 16) & 1u)) >> 16);
}
__device__ __forceinline__ void gload16(const void* g, void* l)
{
    __builtin_amdgcn_global_load_lds((const __attribute__((address_space(1))) unsigned int*)g,
                                     (__attribute__((address_space(3))) unsigned int*)l, 16, 0, 0);
}

// fused prep: blocks 0..127 transpose E (+bf16 cast, enorm, baseq); 128..255 cast X;
// block 256: sum(cs) + loss=0 (sole owner); 257..384: zero ws_sum + bins.
__global__ __launch_bounds__(256) void vq_prep_k(const float* __restrict__ X,
                                                 const float* __restrict__ E,
                                                 const float* __restrict__ CS,
                                                 u16* __restrict__ Xb,
                                                 float* __restrict__ ET32,
                                                 u16* __restrict__ ETb,
                                                 float* __restrict__ enorm,
                                                 float* __restrict__ baseq,
                                                 double* __restrict__ sumcs,
                                                 double* __restrict__ loss,
                                                 char* __restrict__ ws)
{
    const int bid = blockIdx.x;
    const int t = threadIdx.x;

    if (bid < 128) {                       // ---- E transpose + enorm ----
        __shared__ float T[64][65];
        const int j0 = bid * 64;
        const int jc = t >> 2, seg = t & 3;
        const int j = j0 + jc;
        float esum = 0.f;
        for (int d0 = 0; d0 < DIM; d0 += 64) {
            if (d0) __syncthreads();
            #pragma unroll
            for (int p = 0; p < 4; ++p) {
                const int dr = p * 16 + (t >> 4);
                const float4 v = *(const float4*)(E + (size_t)(d0 + dr) * NE + j0 + (t & 15) * 4);
                T[dr][(t & 15) * 4 + 0] = v.x; T[dr][(t & 15) * 4 + 1] = v.y;
                T[dr][(t & 15) * 4 + 2] = v.z; T[dr][(t & 15) * 4 + 3] = v.w;
            }
            __syncthreads();
            float vals[16];
            #pragma unroll
            for (int i = 0; i < 16; ++i) vals[i] = T[seg * 16 + i][jc];
            float4* o32 = (float4*)(ET32 + (size_t)j * DIM + d0 + seg * 16);
            o32[0] = make_float4(vals[0], vals[1], vals[2], vals[3]);
            o32[1] = make_float4(vals[4], vals[5], vals[6], vals[7]);
            o32[2] = make_float4(vals[8], vals[9], vals[10], vals[11]);
            o32[3] = make_float4(vals[12], vals[13], vals[14], vals[15]);
            short8 b0, b1;
            #pragma unroll
            for (int i = 0; i < 8; ++i) { b0[i] = (short)bf16rne(vals[i]); b1[i] = (short)bf16rne(vals[8 + i]); }
            *(short8*)(ETb + (size_t)j * DIM + d0 + seg * 16) = b0;
            *(short8*)(ETb + (size_t)j * DIM + d0 + seg * 16 + 8) = b1;
            #pragma unroll
            for (int i = 0; i < 16; ++i) esum += vals[i] * vals[i];
        }
        esum += __shfl_xor(esum, 1, 4);
        esum += __shfl_xor(esum, 2, 4);
        if (seg == 0) {
            enorm[j] = esum;
            baseq[j] = (esum + 512.f) * 256.f;
        }
    } else if (bid < 256) {                // ---- X -> bf16 ----
        const int chunk = bid - 128;
        #pragma unroll
        for (int it = 0; it < 8; ++it) {
            const int gi = chunk * 2048 + it * 256 + t;
            const float4 a = ((const float4*)X)[gi * 2];
            const float4 b = ((const float4*)X)[gi * 2 + 1];
            short8 v;
            v[0] = (short)bf16rne(a.x); v[1] = (short)bf16rne(a.y);
            v[2] = (short)bf16rne(a.z); v[3] = (short)bf16rne(a.w);
            v[4] = (short)bf16rne(b.x); v[5] = (short)bf16rne(b.y);
            v[6] = (short)bf16rne(b.z); v[7] = (short)bf16rne(b.w);
            *(short8*)(Xb + (size_t)gi * 8) = v;
        }
    } else if (bid == 256) {               // ---- sum(cs) + loss=0 ----
        double s = 0.0;
        #pragma unroll
        for (int it = 0; it < 8; ++it) {
            const float4 v = ((const float4*)CS)[it * 256 + t];
            s += (double)v.x + (double)v.y + (double)v.z + (double)v.w;
        }
        #pragma unroll
        for (int off = 32; off > 0; off >>= 1) s += __shfl_down(s, off);
        __shared__ double wred[4];
        if ((t & 63) == 0) wred[t >> 6] = s;
        __syncthreads();
        if (t == 0) {
            sumcs[0] = wred[0] + wred[1] + wred[2] + wred[3];
            loss[0]  = 0.0;
        }
    } else {                               // ---- zero ws_sum + bins ----
        float4* z = (float4*)(ws + WS_SUM);
        const float4 zv = make_float4(0.f, 0.f, 0.f, 0.f);
        for (int i = (bid - 257) * 256 + t; i < ZERO_F4; i += 128 * 256) z[i] = zv;
    }
}

// Row-stationary approx scan, BARRIER-FREE wave-private pipelines:
//   Each of the 4 waves owns 64 rows (A pinned in AGPR) and a PRIVATE 16KB LDS
//   double-buffer; it stages its own 8KB B-tile (8 x gload16) and runs its own
//   counted-vmcnt pipeline (vmcnt(8), never 0 until tail). No block barriers after
//   the prologue -> waves drift out of phase, so one wave's VALU epilogue overlaps
//   another wave's MFMA on the same SIMD (the R7..R14 lockstep prevented this).
__global__ __launch_bounds__(256, 2) void vq_scan_k(const u16* __restrict__ Xb,
                                                    const u16* __restrict__ ETb,
                                                    const float* __restrict__ baseq,
                                                    unsigned* __restrict__ cand)
{
    __shared__ u16 Bs[4][2][8][512];   // [wave][slot][k8-slice][16 cols x 32 k], 8KB/slot
    __shared__ float Bq[512];          // baseq for this range

    const int tid = threadIdx.x;
    const int w = tid >> 6, l = tid & 63;
    const int lane16 = l & 15, g = l >> 4;
    const int rowbase = blockIdx.x * 256 + w * 64;
    const int c0 = blockIdx.y * 512;

    // publish Bq (the only cross-wave interaction; one prologue barrier)
    *(float2*)&Bq[tid * 2] = *(const float2*)(baseq + c0 + tid * 2);

    // A fragments: lane holds row (l&15) of sub-tile, k-chunk (l>>4)*8, for k8=0..7
    short8 af[4][8];
    #pragma unroll
    for (int sub = 0; sub < 4; ++sub)
        #pragma unroll
        for (int k8 = 0; k8 < 8; ++k8) {
            af[sub][k8] = *(const short8*)(Xb + (size_t)(rowbase + sub * 16 + lane16) * DIM + k8 * 32 + g * 8);
            asm volatile("" : "+a"(af[sub][k8]));   // pin to AGPR (frees arch-VGPR file)
        }

    __syncthreads();   // Bq visible; all prologue loads retired (vmcnt clean)

    unsigned s0[16], s1[16];
    #pragma unroll
    for (int i = 0; i < 16; ++i) { s0[i] = 0xFFFFFFFFu; s1[i] = 0xFFFFFFFFu; }

    // wave-private staging: lane (g,lane16) fetches col c0+t*16+lane16, k-slice s: k=s*32+g*8
    const u16* gsrc = ETb + (size_t)(c0 + lane16) * DIM + g * 8;

    // prologue: stage tiles 0 and 1 into this wave's two slots (stay in flight)
    #pragma unroll
    for (int s = 0; s < 8; ++s) gload16(gsrc + s * 32, &Bs[w][0][s][0]);
    #pragma unroll
    for (int s = 0; s < 8; ++s) gload16(gsrc + 16 * DIM + s * 32, &Bs[w][1][s][0]);

    #pragma unroll 1
    for (int t = 0; t < CTILES; ++t) {
        // counted wait: tile t's 8 loads landed; tile t+1's 8 stay in flight
        if (t < CTILES - 1) asm volatile("s_waitcnt vmcnt(8)" ::: "memory");
        else                asm volatile("s_waitcnt vmcnt(0)" ::: "memory");

        const int slot = t & 1;
        const float bq = Bq[t * 16 + lane16];
        f32x4 acc[4];
        #pragma unroll
        for (int sub = 0; sub < 4; ++sub) acc[sub] = {0.f, 0.f, 0.f, 0.f};
        #pragma unroll
        for (int k8 = 0; k8 < 8; ++k8) {
            const short8 bf = *(const short8*)&Bs[w][slot][k8][l * 8];
            #pragma unroll
            for (int sub = 0; sub < 4; ++sub)
                acc[sub] = __builtin_amdgcn_mfma_f32_16x16x32_bf16(af[sub][k8], bf, acc[sub], 0, 0, 0);
        }

        // this wave's reads of `slot` are done -> safe to overwrite with tile t+2
        asm volatile("s_waitcnt lgkmcnt(0)" ::: "memory");
        if (t + 2 < CTILES) {
            const u16* nsrc = gsrc + (size_t)(t + 2) * 16 * DIM;
            #pragma unroll
            for (int s = 0; s < 8; ++s) gload16(nsrc + s * 32, &Bs[w][slot][s][0]);
        }

        // epilogue: pack key and update sorted top-2 (runs while t+2's DMA flies)
        const int col = c0 + t * 16 + lane16;
        #pragma unroll
        for (int sub = 0; sub < 4; ++sub)
            #pragma unroll
            for (int r = 0; r < 4; ++r) {
                const int i = sub * 4 + r;
                const float qf = fmaf(acc[sub][r], -512.f, bq);  // (enorm - 2*dot + 512) * 256
                const unsigned key = (((unsigned)qf) << 13) | (unsigned)col;
                const unsigned tt = max(s0[i], key);
                s0[i] = min(s0[i], key);
                s1[i] = min(s1[i], tt);
            }
    }

    // merge sorted pairs across the 16 lanes of each g-group
    #pragma unroll
    for (int m = 1; m < 16; m <<= 1) {
        #pragma unroll
        for (int i = 0; i < 16; ++i) {
            const unsigned o0 = __shfl_xor(s0[i], m);
            const unsigned o1 = __shfl_xor(s1[i], m);
            const unsigned t0 = min(s0[i], o0);
            const unsigned t1 = min(max(s0[i], o0), min(s1[i], o1));
            s0[i] = t0; s1[i] = t1;
        }
    }
    if (lane16 == 0) {
        #pragma unroll
        for (int i = 0; i < 16; ++i) {
            const int row = rowbase + (i >> 2) * 16 + g * 4 + (i & 3);
            cand[((size_t)row * CRANGES + blockIdx.y) * 2 + 0] = s0[i];
            cand[((size_t)row * CRANGES + blockIdx.y) * 2 + 1] = s1[i];
        }
    }
}

// fused: exact f32 re-rank (one wave per row) + quantize/stats epilogue (256 threads over d)
__global__ __launch_bounds__(256) void vq_finalize_k(const unsigned* __restrict__ cand,
                                                     const float* __restrict__ X,
                                                     const float* __restrict__ ET32,
                                                     const float* __restrict__ enorm,
                                                     float* __restrict__ out_q,
                                                     float* __restrict__ out_ind,
                                                     float* __restrict__ ws_sum,
                                                     float* __restrict__ bins,
                                                     double* __restrict__ loss)
{
    __shared__ int sj[4];
    const int tid = threadIdx.x;
    const int w = tid >> 6, l = tid & 63;
    const int row = blockIdx.x * 4 + w;

    unsigned key = 0xFFFFFFFFu;
    if (l < 32) key = cand[(size_t)row * 32 + l];
    unsigned qmin = key;
    #pragma unroll
    for (int m = 32; m; m >>= 1) qmin = min(qmin, __shfl_xor(qmin, m));
    const unsigned qthr = (qmin >> 13) + MQ;
    unsigned long long mask = __ballot((l < 32) && ((key >> 13) <= qthr));
    const float4 xv = *(const float4*)(X + (size_t)row * DIM + l * 4);
    unsigned long long best = 0xFFFFFFFFFFFFFFFFull;
    while (mask) {
        const int src = __builtin_ctzll(mask);
        mask &= mask - 1;
        const int col = (int)(__shfl(key, src) & 8191u);
        const float4 ev = *(const float4*)(ET32 + (size_t)col * DIM + l * 4);
        float s = xv.x * ev.x + xv.y * ev.y + xv.z * ev.z + xv.w * ev.w;
        #pragma unroll
        for (int m = 32; m; m >>= 1) s += __shfl_xor(s, m);
        const float d = enorm[col] - 2.f * s;
        const unsigned long long k64 = ((unsigned long long)f32_ord(d) << 32) | (unsigned)col;
        best = (k64 < best) ? k64 : best;
    }
    if (l == 0) {
        const int j = (int)(best & 8191u);
        sj[w] = j;
        out_ind[row] = (float)j;
    }
    __syncthreads();

    float lsum = 0.f;
    #pragma unroll
    for (int q = 0; q < 4; ++q) {
        const int r = blockIdx.x * 4 + q;
        const int j = sj[q];
        const float x  = X[(size_t)r * DIM + tid];
        const float qv = ET32[(size_t)j * DIM + tid];
        out_q[(size_t)r * DIM + tid] = x + (qv - x);
        const float d = qv - x;
        lsum += d * d;
        atomicAdd(&ws_sum[(size_t)j * DIM + tid], x);
        if (tid == 0) atomicAdd(&bins[j], 1.0f);
    }
    #pragma unroll
    for (int off = 32; off > 0; off >>= 1) lsum += __shfl_down(lsum, off);
    __shared__ double wred[4];
    if ((tid & 63) == 0) wred[tid >> 6] = (double)lsum;
    __syncthreads();
    if (tid == 0) atomicAdd(loss, wred[0] + wred[1] + wred[2] + wred[3]);
}

// embed update; also emits out_csn (y==0 blocks) and out_loss (block (0,0)).
// S = sum(csn) = DECAY*sum(cs) + (1-DECAY)*NROWS  (sum(bins) == NROWS exactly).
__global__ __launch_bounds__(256) void vq_embed_k(const float* __restrict__ EA,
                                                  const float* __restrict__ cs,
                                                  const float* __restrict__ bins,
                                                  const float* __restrict__ ws_sum,
                                                  const double* __restrict__ sumcs,
                                                  const double* __restrict__ loss,
                                                  float* __restrict__ out_norm,
                                                  float* __restrict__ out_avg,
                                                  float* __restrict__ out_csn,
                                                  float* __restrict__ out_loss)
{
    __shared__ float T[64][69];
    const int tid = threadIdx.x;
    const int j0 = blockIdx.x * 64;
    const int d0 = blockIdx.y * 64;
    #pragma unroll
    for (int p = 0; p < 4; ++p) {
        const int jr = (tid >> 4) + p * 16;
        const int dc = (tid & 15) * 4;
        const float4 v = *(const float4*)(ws_sum + (size_t)(j0 + jr) * DIM + d0 + dc);
        T[jr][dc + 0] = v.x; T[jr][dc + 1] = v.y; T[jr][dc + 2] = v.z; T[jr][dc + 3] = v.w;
    }
    __syncthreads();
    const double S = (double)DECAY * sumcs[0] + (double)(1.0f - DECAY) * (double)NROWS;
    const float fac = (float)(S / (S + (double)NE * 1e-5));
    const int jc = tid & 63;
    const int j  = j0 + jc;
    const float csn  = cs[j] * DECAY + (1.0f - DECAY) * bins[j];
    const float cs_j = (csn + EPS_F) * fac;
    if (blockIdx.y == 0 && tid < 64) out_csn[j0 + tid] = cs[j0 + tid] * DECAY + (1.0f - DECAY) * bins[j0 + tid];
    if (blockIdx.y == 0 && blockIdx.x == 0 && tid == 0) out_loss[0] = (float)(loss[0] * (1.0 / 2097152.0));
    const int drb = (tid >> 6) * 16;
    #pragma unroll
    for (int p = 0; p < 16; ++p) {
        const int dr = drb + p;
        const float sum = T[jc][dr];
        const float ea  = EA[(size_t)(d0 + dr) * NE + j];
        const float ean = DECAY * ea + (1.0f - DECAY) * sum;
        out_avg[(size_t)(d0 + dr) * NE + j]  = ean;
        out_norm[(size_t)(d0 + dr) * NE + j] = ean / cs_j;
    }
}

extern "C" void kernel_launch(void* const* d_in, const int* in_sizes, int n_in,
                              void* d_out, int out_size, void* d_ws, size_t ws_size,
                              hipStream_t stream)
{
    const float* X  = (const float*)d_in[0];
    const float* E  = (const float*)d_in[1];
    const float* CS = (const float*)d_in[2];
    const float* EA = (const float*)d_in[3];
    float* out = (float*)d_out;
    char*  ws  = (char*)d_ws;

    unsigned* cand  = (unsigned*)(ws + WS_CAND);
    float*  enorm  = (float*)(ws + WS_ENORM);
    float*  baseq  = (float*)(ws + WS_BASEQ);
    float*  ws_sum = (float*)(ws + WS_SUM);
    float*  bins   = (float*)(ws + WS_BINS);
    double* loss   = (double*)(ws + WS_LOSS);
    double* sumcs  = (double*)(ws + WS_SCS);
    u16*    Xb     = (u16*)(ws + WS_XB);
    u16*    ETb    = (u16*)(ws + WS_ETB);
    float*  ET32   = (float*)(ws + WS_ET32);

    vq_prep_k<<<385, 256, 0, stream>>>(X, E, CS, Xb, ET32, ETb, enorm, baseq, sumcs, loss, ws);
    vq_scan_k<<<dim3(NROWS / 256, CRANGES), 256, 0, stream>>>(Xb, ETb, baseq, cand);
    vq_finalize_k<<<NROWS / 4, 256, 0, stream>>>(cand, X, ET32, enorm, out + OUT_Q, out + OUT_IND, ws_sum, bins, loss);
    vq_embed_k<<<dim3(NE / 64, DIM / 64), 256, 0, stream>>>(EA, CS, bins, ws_sum, sumcs, loss,
                                                            out + OUT_NORM, out + OUT_AVG, out + OUT_CSN, out + OUT_LOSS);
}

// Round 16
// 97.382 us; speedup vs baseline: 1.2798x; 1.2798x over previous
//
#include <hip/hip_runtime.h>

typedef unsigned short u16;
typedef __attribute__((ext_vector_type(8))) short short8;
typedef __attribute__((ext_vector_type(4))) float f32x4;

#define DIM    256
#define NE     8192
#define NROWS  8192
#define DECAY  0.1f
#define EPS_F  1e-5f
#define CRANGES 16      // column ranges of 512
#define CPAIRS  16      // 2-tile phases per range (32 cols per phase)
#define MQ      384u    // refine margin: 1.5 distance units (q step = 1/256)

// output offsets (floats): quantize_st, embed_ind, loss, embed_normalized, cluster_size_new, embed_avg_new
#define OUT_Q    0
#define OUT_IND  2097152
#define OUT_LOSS 2105344
#define OUT_NORM 2105345
#define OUT_CSN  4202497
#define OUT_AVG  4210689

// ws offsets (bytes)
#define WS_CAND  65536      // u32[8192*32] top-2 per (row, range)
#define WS_ENORM 1114112    // f32[8192]
#define WS_BASEQ 1146880    // f32[8192]  (enorm + 512) * 256
#define WS_SUM   1179648    // f32[8192*256] transposed segment sums
#define WS_BINS  9568256    // f32[8192]
#define WS_LOSS  9601024    // f64
#define WS_SCS   9601032    // f64  sum(cluster_size)
#define WS_XB    9601040    // bf16[8192*256]
#define WS_ETB   13795344   // bf16[8192*256] E^T (k-contiguous)
#define WS_ET32  17989648   // f32[8192*256]  E^T
#define ZERO_F4  ((WS_LOSS - WS_SUM) / 16)  // prep zero-blocks: ws_sum + bins ONLY

__device__ __forceinline__ unsigned f32_ord(float f)
{
    unsigned u = __float_as_uint(f);
    return (u & 0x80000000u) ? ~u : (u | 0x80000000u);
}
__device__ __forceinline__ u16 bf16rne(float f)
{
    unsigned u = __float_as_uint(f);
    return (u16)((u + 0x7fffu + ((u >> 16) & 1u)) >> 16);
}
__device__ __forceinline__ void gload16(const void* g, void* l)
{
    __builtin_amdgcn_global_load_lds((const __attribute__((address_space(1))) unsigned int*)g,
                                     (__attribute__((address_space(3))) unsigned int*)l, 16, 0, 0);
}

// fused prep: blocks 0..127 transpose E (+bf16 cast, enorm, baseq); 128..255 cast X;
// block 256: sum(cs) + loss=0 (sole owner); 257..384: zero ws_sum + bins.
__global__ __launch_bounds__(256) void vq_prep_k(const float* __restrict__ X,
                                                 const float* __restrict__ E,
                                                 const float* __restrict__ CS,
                                                 u16* __restrict__ Xb,
                                                 float* __restrict__ ET32,
                                                 u16* __restrict__ ETb,
                                                 float* __restrict__ enorm,
                                                 float* __restrict__ baseq,
                                                 double* __restrict__ sumcs,
                                                 double* __restrict__ loss,
                                                 char* __restrict__ ws)
{
    const int bid = blockIdx.x;
    const int t = threadIdx.x;

    if (bid < 128) {                       // ---- E transpose + enorm ----
        __shared__ float T[64][65];
        const int j0 = bid * 64;
        const int jc = t >> 2, seg = t & 3;
        const int j = j0 + jc;
        float esum = 0.f;
        for (int d0 = 0; d0 < DIM; d0 += 64) {
            if (d0) __syncthreads();
            #pragma unroll
            for (int p = 0; p < 4; ++p) {
                const int dr = p * 16 + (t >> 4);
                const float4 v = *(const float4*)(E + (size_t)(d0 + dr) * NE + j0 + (t & 15) * 4);
                T[dr][(t & 15) * 4 + 0] = v.x; T[dr][(t & 15) * 4 + 1] = v.y;
                T[dr][(t & 15) * 4 + 2] = v.z; T[dr][(t & 15) * 4 + 3] = v.w;
            }
            __syncthreads();
            float vals[16];
            #pragma unroll
            for (int i = 0; i < 16; ++i) vals[i] = T[seg * 16 + i][jc];
            float4* o32 = (float4*)(ET32 + (size_t)j * DIM + d0 + seg * 16);
            o32[0] = make_float4(vals[0], vals[1], vals[2], vals[3]);
            o32[1] = make_float4(vals[4], vals[5], vals[6], vals[7]);
            o32[2] = make_float4(vals[8], vals[9], vals[10], vals[11]);
            o32[3] = make_float4(vals[12], vals[13], vals[14], vals[15]);
            short8 b0, b1;
            #pragma unroll
            for (int i = 0; i < 8; ++i) { b0[i] = (short)bf16rne(vals[i]); b1[i] = (short)bf16rne(vals[8 + i]); }
            *(short8*)(ETb + (size_t)j * DIM + d0 + seg * 16) = b0;
            *(short8*)(ETb + (size_t)j * DIM + d0 + seg * 16 + 8) = b1;
            #pragma unroll
            for (int i = 0; i < 16; ++i) esum += vals[i] * vals[i];
        }
        esum += __shfl_xor(esum, 1, 4);
        esum += __shfl_xor(esum, 2, 4);
        if (seg == 0) {
            enorm[j] = esum;
            baseq[j] = (esum + 512.f) * 256.f;
        }
    } else if (bid < 256) {                // ---- X -> bf16 ----
        const int chunk = bid - 128;
        #pragma unroll
        for (int it = 0; it < 8; ++it) {
            const int gi = chunk * 2048 + it * 256 + t;
            const float4 a = ((const float4*)X)[gi * 2];
            const float4 b = ((const float4*)X)[gi * 2 + 1];
            short8 v;
            v[0] = (short)bf16rne(a.x); v[1] = (short)bf16rne(a.y);
            v[2] = (short)bf16rne(a.z); v[3] = (short)bf16rne(a.w);
            v[4] = (short)bf16rne(b.x); v[5] = (short)bf16rne(b.y);
            v[6] = (short)bf16rne(b.z); v[7] = (short)bf16rne(b.w);
            *(short8*)(Xb + (size_t)gi * 8) = v;
        }
    } else if (bid == 256) {               // ---- sum(cs) + loss=0 ----
        double s = 0.0;
        #pragma unroll
        for (int it = 0; it < 8; ++it) {
            const float4 v = ((const float4*)CS)[it * 256 + t];
            s += (double)v.x + (double)v.y + (double)v.z + (double)v.w;
        }
        #pragma unroll
        for (int off = 32; off > 0; off >>= 1) s += __shfl_down(s, off);
        __shared__ double wred[4];
        if ((t & 63) == 0) wred[t >> 6] = s;
        __syncthreads();
        if (t == 0) {
            sumcs[0] = wred[0] + wred[1] + wred[2] + wred[3];
            loss[0]  = 0.0;
        }
    } else {                               // ---- zero ws_sum + bins ----
        float4* z = (float4*)(ws + WS_SUM);
        const float4 zv = make_float4(0.f, 0.f, 0.f, 0.f);
        for (int i = (bid - 257) * 256 + t; i < ZERO_F4; i += 128 * 256) z[i] = zv;
    }
}

// Row-stationary approx scan — R7's exact measured-best config (50.1 us):
//   block = 4 waves x 64 rows = 256 rows x 512-col range; af[4][8] pinned "+v";
//   pair-staging at phase top into the other 16KB buffer, compute both halves,
//   single vmcnt(0)+barrier at phase END. 2 blocks/CU; blocks drift out of phase
//   to overlap MFMA with the top-2 VALU epilogue across SIMD co-residents.
__global__ __launch_bounds__(256, 2) void vq_scan_k(const u16* __restrict__ Xb,
                                                    const u16* __restrict__ ETb,
                                                    const float* __restrict__ baseq,
                                                    unsigned* __restrict__ cand)
{
    __shared__ u16 Bs[2][16][512]; // [buf][tile-in-pair*8 + k-slice][16 cols x 32 k], 16KB/buf

    const int tid = threadIdx.x;
    const int w = tid >> 6, l = tid & 63;
    const int lane16 = l & 15, g = l >> 4;
    const int rowbase = blockIdx.x * 256 + w * 64;
    const int c0 = blockIdx.y * 512;

    // A fragments: lane holds row (l&15) of sub-tile, k-chunk (l>>4)*8, for k8=0..7
    short8 af[4][8];
    #pragma unroll
    for (int sub = 0; sub < 4; ++sub)
        #pragma unroll
        for (int k8 = 0; k8 < 8; ++k8) {
            af[sub][k8] = *(const short8*)(Xb + (size_t)(rowbase + sub * 16 + lane16) * DIM + k8 * 32 + g * 8);
            asm volatile("" : "+v"(af[sub][k8]));   // keepalive (R7 config)
        }

    unsigned s0[16], s1[16];
    #pragma unroll
    for (int i = 0; i < 16; ++i) { s0[i] = 0xFFFFFFFFu; s1[i] = 0xFFFFFFFFu; }

    // staging: wave w owns k-slices 2w, 2w+1 of each tile; lane (g,col) fetches its own 16B
    const u16* gsrc = ETb + (size_t)(c0 + lane16) * DIM + (size_t)w * 64 + g * 8;

    // prologue: stage pair 0 (tiles 0,1)
    gload16(gsrc,                 &Bs[0][2 * w + 0][0]);
    gload16(gsrc + 32,            &Bs[0][2 * w + 1][0]);
    gload16(gsrc + 16 * DIM,      &Bs[0][8 + 2 * w + 0][0]);
    gload16(gsrc + 16 * DIM + 32, &Bs[0][8 + 2 * w + 1][0]);
    asm volatile("s_waitcnt vmcnt(0)" ::: "memory");
    __builtin_amdgcn_s_barrier();

    int buf = 0;
    #pragma unroll 1
    for (int p = 0; p < CPAIRS; ++p) {
        if (p + 1 < CPAIRS) { // stage next pair into the other buffer
            const u16* nsrc = gsrc + (size_t)(p + 1) * 32 * DIM;
            gload16(nsrc,                 &Bs[buf ^ 1][2 * w + 0][0]);
            gload16(nsrc + 32,            &Bs[buf ^ 1][2 * w + 1][0]);
            gload16(nsrc + 16 * DIM,      &Bs[buf ^ 1][8 + 2 * w + 0][0]);
            gload16(nsrc + 16 * DIM + 32, &Bs[buf ^ 1][8 + 2 * w + 1][0]);
        }
        #pragma unroll
        for (int half = 0; half < 2; ++half) {
            const int col = c0 + (p * 2 + half) * 16 + lane16;
            const float bq = baseq[col];
            f32x4 acc[4];
            #pragma unroll
            for (int sub = 0; sub < 4; ++sub) acc[sub] = {0.f, 0.f, 0.f, 0.f};
            #pragma unroll
            for (int k8 = 0; k8 < 8; ++k8) {
                const short8 bf = *(const short8*)&Bs[buf][half * 8 + k8][l * 8];
                #pragma unroll
                for (int sub = 0; sub < 4; ++sub)
                    acc[sub] = __builtin_amdgcn_mfma_f32_16x16x32_bf16(af[sub][k8], bf, acc[sub], 0, 0, 0);
            }
            #pragma unroll
            for (int sub = 0; sub < 4; ++sub)
                #pragma unroll
                for (int r = 0; r < 4; ++r) {
                    const int i = sub * 4 + r;
                    const float qf = fmaf(acc[sub][r], -512.f, bq);  // (enorm - 2*dot + 512) * 256
                    const unsigned key = (((unsigned)qf) << 13) | (unsigned)col;
                    const unsigned tt = max(s0[i], key);
                    s0[i] = min(s0[i], key);
                    s1[i] = min(s1[i], tt);
                }
        }
        asm volatile("s_waitcnt vmcnt(0)" ::: "memory");
        __builtin_amdgcn_s_barrier();
        buf ^= 1;
    }

    // merge sorted pairs across the 16 lanes of each g-group
    #pragma unroll
    for (int m = 1; m < 16; m <<= 1) {
        #pragma unroll
        for (int i = 0; i < 16; ++i) {
            const unsigned o0 = __shfl_xor(s0[i], m);
            const unsigned o1 = __shfl_xor(s1[i], m);
            const unsigned t0 = min(s0[i], o0);
            const unsigned t1 = min(max(s0[i], o0), min(s1[i], o1));
            s0[i] = t0; s1[i] = t1;
        }
    }
    if (lane16 == 0) {
        #pragma unroll
        for (int i = 0; i < 16; ++i) {
            const int row = rowbase + (i >> 2) * 16 + g * 4 + (i & 3);
            cand[((size_t)row * CRANGES + blockIdx.y) * 2 + 0] = s0[i];
            cand[((size_t)row * CRANGES + blockIdx.y) * 2 + 1] = s1[i];
        }
    }
}

// fused: exact f32 re-rank (one wave per row) + quantize/stats epilogue (256 threads over d)
__global__ __launch_bounds__(256) void vq_finalize_k(const unsigned* __restrict__ cand,
                                                     const float* __restrict__ X,
                                                     const float* __restrict__ ET32,
                                                     const float* __restrict__ enorm,
                                                     float* __restrict__ out_q,
                                                     float* __restrict__ out_ind,
                                                     float* __restrict__ ws_sum,
                                                     float* __restrict__ bins,
                                                     double* __restrict__ loss)
{
    __shared__ int sj[4];
    const int tid = threadIdx.x;
    const int w = tid >> 6, l = tid & 63;
    const int row = blockIdx.x * 4 + w;

    unsigned key = 0xFFFFFFFFu;
    if (l < 32) key = cand[(size_t)row * 32 + l];
    unsigned qmin = key;
    #pragma unroll
    for (int m = 32; m; m >>= 1) qmin = min(qmin, __shfl_xor(qmin, m));
    const unsigned qthr = (qmin >> 13) + MQ;
    unsigned long long mask = __ballot((l < 32) && ((key >> 13) <= qthr));
    const float4 xv = *(const float4*)(X + (size_t)row * DIM + l * 4);
    unsigned long long best = 0xFFFFFFFFFFFFFFFFull;
    while (mask) {
        const int src = __builtin_ctzll(mask);
        mask &= mask - 1;
        const int col = (int)(__shfl(key, src) & 8191u);
        const float4 ev = *(const float4*)(ET32 + (size_t)col * DIM + l * 4);
        float s = xv.x * ev.x + xv.y * ev.y + xv.z * ev.z + xv.w * ev.w;
        #pragma unroll
        for (int m = 32; m; m >>= 1) s += __shfl_xor(s, m);
        const float d = enorm[col] - 2.f * s;
        const unsigned long long k64 = ((unsigned long long)f32_ord(d) << 32) | (unsigned)col;
        best = (k64 < best) ? k64 : best;
    }
    if (l == 0) {
        const int j = (int)(best & 8191u);
        sj[w] = j;
        out_ind[row] = (float)j;
    }
    __syncthreads();

    float lsum = 0.f;
    #pragma unroll
    for (int q = 0; q < 4; ++q) {
        const int r = blockIdx.x * 4 + q;
        const int j = sj[q];
        const float x  = X[(size_t)r * DIM + tid];
        const float qv = ET32[(size_t)j * DIM + tid];
        out_q[(size_t)r * DIM + tid] = x + (qv - x);
        const float d = qv - x;
        lsum += d * d;
        atomicAdd(&ws_sum[(size_t)j * DIM + tid], x);
        if (tid == 0) atomicAdd(&bins[j], 1.0f);
    }
    #pragma unroll
    for (int off = 32; off > 0; off >>= 1) lsum += __shfl_down(lsum, off);
    __shared__ double wred[4];
    if ((tid & 63) == 0) wred[tid >> 6] = (double)lsum;
    __syncthreads();
    if (tid == 0) atomicAdd(loss, wred[0] + wred[1] + wred[2] + wred[3]);
}

// embed update; also emits out_csn (y==0 blocks) and out_loss (block (0,0)).
// S = sum(csn) = DECAY*sum(cs) + (1-DECAY)*NROWS  (sum(bins) == NROWS exactly).
__global__ __launch_bounds__(256) void vq_embed_k(const float* __restrict__ EA,
                                                  const float* __restrict__ cs,
                                                  const float* __restrict__ bins,
                                                  const float* __restrict__ ws_sum,
                                                  const double* __restrict__ sumcs,
                                                  const double* __restrict__ loss,
                                                  float* __restrict__ out_norm,
                                                  float* __restrict__ out_avg,
                                                  float* __restrict__ out_csn,
                                                  float* __restrict__ out_loss)
{
    __shared__ float T[64][69];
    const int tid = threadIdx.x;
    const int j0 = blockIdx.x * 64;
    const int d0 = blockIdx.y * 64;
    #pragma unroll
    for (int p = 0; p < 4; ++p) {
        const int jr = (tid >> 4) + p * 16;
        const int dc = (tid & 15) * 4;
        const float4 v = *(const float4*)(ws_sum + (size_t)(j0 + jr) * DIM + d0 + dc);
        T[jr][dc + 0] = v.x; T[jr][dc + 1] = v.y; T[jr][dc + 2] = v.z; T[jr][dc + 3] = v.w;
    }
    __syncthreads();
    const double S = (double)DECAY * sumcs[0] + (double)(1.0f - DECAY) * (double)NROWS;
    const float fac = (float)(S / (S + (double)NE * 1e-5));
    const int jc = tid & 63;
    const int j  = j0 + jc;
    const float csn  = cs[j] * DECAY + (1.0f - DECAY) * bins[j];
    const float cs_j = (csn + EPS_F) * fac;
    if (blockIdx.y == 0 && tid < 64) out_csn[j0 + tid] = cs[j0 + tid] * DECAY + (1.0f - DECAY) * bins[j0 + tid];
    if (blockIdx.y == 0 && blockIdx.x == 0 && tid == 0) out_loss[0] = (float)(loss[0] * (1.0 / 2097152.0));
    const int drb = (tid >> 6) * 16;
    #pragma unroll
    for (int p = 0; p < 16; ++p) {
        const int dr = drb + p;
        const float sum = T[jc][dr];
        const float ea  = EA[(size_t)(d0 + dr) * NE + j];
        const float ean = DECAY * ea + (1.0f - DECAY) * sum;
        out_avg[(size_t)(d0 + dr) * NE + j]  = ean;
        out_norm[(size_t)(d0 + dr) * NE + j] = ean / cs_j;
    }
}

extern "C" void kernel_launch(void* const* d_in, const int* in_sizes, int n_in,
                              void* d_out, int out_size, void* d_ws, size_t ws_size,
                              hipStream_t stream)
{
    const float* X  = (const float*)d_in[0];
    const float* E  = (const float*)d_in[1];
    const float* CS = (const float*)d_in[2];
    const float* EA = (const float*)d_in[3];
    float* out = (float*)d_out;
    char*  ws  = (char*)d_ws;

    unsigned* cand  = (unsigned*)(ws + WS_CAND);
    float*  enorm  = (float*)(ws + WS_ENORM);
    float*  baseq  = (float*)(ws + WS_BASEQ);
    float*  ws_sum = (float*)(ws + WS_SUM);
    float*  bins   = (float*)(ws + WS_BINS);
    double* loss   = (double*)(ws + WS_LOSS);
    double* sumcs  = (double*)(ws + WS_SCS);
    u16*    Xb     = (u16*)(ws + WS_XB);
    u16*    ETb    = (u16*)(ws + WS_ETB);
    float*  ET32   = (float*)(ws + WS_ET32);

    vq_prep_k<<<385, 256, 0, stream>>>(X, E, CS, Xb, ET32, ETb, enorm, baseq, sumcs, loss, ws);
    vq_scan_k<<<dim3(NROWS / 256, CRANGES), 256, 0, stream>>>(Xb, ETb, baseq, cand);
    vq_finalize_k<<<NROWS / 4, 256, 0, stream>>>(cand, X, ET32, enorm, out + OUT_Q, out + OUT_IND, ws_sum, bins, loss);
    vq_embed_k<<<dim3(NE / 64, DIM / 64), 256, 0, stream>>>(EA, CS, bins, ws_sum, sumcs, loss,
                                                            out + OUT_NORM, out + OUT_AVG, out + OUT_CSN, out + OUT_LOSS);
}